// Round 1
// 536.554 us; speedup vs baseline: 1.1252x; 1.1252x over previous
//
#include <hip/hip_runtime.h>
#include <math.h>

typedef unsigned short u16;
typedef unsigned int u32;

#define D_EMB 768
#define F_HID 3072
#define N_TOK 4096
#define N_PAIR 8192
#define GATE_TH 1e-9f

typedef float f32x4 __attribute__((ext_vector_type(4)));
typedef __bf16 bfrag __attribute__((ext_vector_type(8)));

__device__ inline float b2f(u16 u) {
    union { float f; u32 i; } c; c.i = ((u32)u) << 16; return c.f;
}
__device__ inline u16 f2b(float f) {
    union { float f; u32 i; } c; c.f = f;
    u32 r = c.i + 0x7FFFu + ((c.i >> 16) & 1u);   // round-nearest-even
    return (u16)(r >> 16);
}
__device__ inline f32x4 mfma16(bfrag a, bfrag b, f32x4 c) {
    return __builtin_amdgcn_mfma_f32_16x16x32_bf16(a, b, c, 0, 0, 0);
}
// async global->LDS, 16B per lane. LDS dest = wave-uniform base + lane*16.
__device__ inline void gll16(const u16* g, u16* l) {
    __builtin_amdgcn_global_load_lds(
        (const __attribute__((address_space(1))) u32*)g,
        (__attribute__((address_space(3))) u32*)l, 16, 0, 0);
}

// ---------------------------------------------------------------- init / zero
__global__ void moe_init_kernel(int* __restrict__ cnt) {
    if (threadIdx.x < 8) cnt[threadIdx.x] = 0;
}
__global__ __launch_bounds__(256) void moe_zero_kernel(uint4* __restrict__ out) {
    int i = blockIdx.x * 256 + threadIdx.x;   // 786432 uint4 = 12.58 MB (fp32 out)
    out[i] = make_uint4(0, 0, 0, 0);
}

// ---------------------------------------------------------------- router (fp32)
__global__ __launch_bounds__(256) void moe_router_f32(
    const float* __restrict__ x, const float* __restrict__ noise,
    const float* __restrict__ Wg, const float* __restrict__ bg,
    const float* __restrict__ Wn, const float* __restrict__ bn,
    int* __restrict__ tk_e, float* __restrict__ tk_g, int* __restrict__ cnt)
{
    const int t = blockIdx.x * 4 + (threadIdx.x >> 6);
    const int lane = threadIdx.x & 63;
    float ag[8] = {}, an[8] = {};
    for (int i = 0; i < 12; i++) {
        int k = i * 64 + lane;
        float xv = x[(size_t)t * D_EMB + k];
        const float* wgp = Wg + k * 8;
        const float* wnp = Wn + k * 8;
#pragma unroll
        for (int e = 0; e < 8; e++) {
            ag[e] += xv * wgp[e];
            an[e] += xv * wnp[e];
        }
    }
#pragma unroll
    for (int e = 0; e < 8; e++) {
        float vg = ag[e], vn = an[e];
        for (int s = 32; s; s >>= 1) { vg += __shfl_xor(vg, s); vn += __shfl_xor(vn, s); }
        ag[e] = vg; an[e] = vn;
    }
    if (lane == 0) {
        float best = -INFINITY, sec = -INFINITY; int be = 0, se = 0;
#pragma unroll
        for (int e = 0; e < 8; e++) {
            float nl = an[e] + bn[e];
            float sp = nl > 0.f ? nl + log1pf(expf(-nl)) : log1pf(expf(nl));  // softplus
            float v = ag[e] + bg[e] + noise[(size_t)t * 8 + e] * sp;
            if (v > best) { sec = best; se = be; best = v; be = e; }
            else if (v > sec) { sec = v; se = e; }
        }
        float ex = expf(sec - best);
        float g1 = 1.f / (1.f + ex), g2 = ex / (1.f + ex);
        tk_e[t * 2 + 0] = (g1 > GATE_TH) ? be : -1; tk_g[t * 2 + 0] = g1;
        tk_e[t * 2 + 1] = (g2 > GATE_TH) ? se : -1; tk_g[t * 2 + 1] = g2;
        if (g1 > GATE_TH) atomicAdd(&cnt[be], 1);
        if (g2 > GATE_TH) atomicAdd(&cnt[se], 1);
    }
}

// ---------------------------------------------------------------- offsets / scatter
__global__ void moe_offsets_kernel(const int* __restrict__ cnt,
                                   int* __restrict__ off, int* __restrict__ cursor) {
    if (threadIdx.x == 0) {
        int s = 0;
        for (int e = 0; e < 8; e++) { off[e] = s; cursor[e] = s; s += cnt[e]; }
    }
}
__global__ void moe_scatter_kernel(const int* __restrict__ tk_e, const float* __restrict__ tk_g,
                                   int* __restrict__ cursor, int* __restrict__ plist,
                                   float* __restrict__ pg, int* __restrict__ pos) {
    int i = blockIdx.x * 256 + threadIdx.x;
    if (i < N_PAIR) {
        int e = tk_e[i];
        if (e >= 0) {
            int p = atomicAdd(&cursor[e], 1);
            plist[p] = i >> 1;
            pg[p] = tk_g[i];
            pos[i] = p;
        }
    }
}

// ---------------------------------------------------------------- x -> bf16
__global__ __launch_bounds__(256) void moe_cvtx_kernel(
    const float4* __restrict__ x, ushort4* __restrict__ xb) {
    int i = blockIdx.x * 256 + threadIdx.x;   // 786432
    float4 v = x[i];
    ushort4 o;
    o.x = f2b(v.x); o.y = f2b(v.y); o.z = f2b(v.z); o.w = f2b(v.w);
    xb[i] = o;
}

// ---------------------------------------------------------------- transpose+convert
// in fp32 [Z][R][C] -> out bf16 [Z][C][R]
__global__ __launch_bounds__(256) void moe_transcvt_kernel(
    const float* __restrict__ in, u16* __restrict__ out, int R, int C) {
    __shared__ float tile[32][33];
    const int z = blockIdx.z;
    const int c0 = blockIdx.x * 32, r0 = blockIdx.y * 32;
    const int tx = threadIdx.x & 31, ty = threadIdx.x >> 5;   // ty 0..7
    const size_t base = (size_t)z * R * C;
#pragma unroll
    for (int j = 0; j < 32; j += 8)
        tile[ty + j][tx] = in[base + (size_t)(r0 + ty + j) * C + c0 + tx];
    __syncthreads();
#pragma unroll
    for (int j = 0; j < 32; j += 8)
        out[base + (size_t)(c0 + ty + j) * R + r0 + tx] = f2b(tile[tx][ty + j]);
}

// ---------------------------------------------------------------- FFN1 GEMM
// h[p-P0] = relu(xb[plist[p]] . w1t[e]^T + b1[e]); 128x128x32 tiles, 4 waves.
// Staging via global_load_lds (linear dest); bank-conflict-free via source-side
// quad swizzle: LDS[row][quad] holds global quad (quad ^ ((row>>1)&3)).
__global__ __launch_bounds__(256) void moe_ffn1_kernel(
    const u16* __restrict__ xb, const u16* __restrict__ w1t, const float* __restrict__ b1,
    const int* __restrict__ plist, const int* __restrict__ cnt, const int* __restrict__ off,
    u16* __restrict__ h, int P0, int P1)
{
    __shared__ __align__(16) u16 As[128 * 32];
    __shared__ __align__(16) u16 Bs[128 * 32];
    const int e = blockIdx.z;
    int lo = off[e], hi = lo + cnt[e];
    if (lo < P0) lo = P0;
    if (hi > P1) hi = P1;
    const int Cl = hi - lo;
    if (Cl <= 0) return;
    const int n0 = blockIdx.x * 128;
    const int tid = threadIdx.x;
    const int lane = tid & 63, wave = tid >> 6;
    const int wr = wave >> 1, wc = wave & 1;
    const int q = lane >> 4, r = lane & 15;
    const int qa = (q ^ ((r >> 1) & 3)) * 8;            // swizzled read quad (u16)
    const int srow = tid >> 2;                          // staging row (j=0); j=1: +64
    const int skq = ((tid & 3) ^ ((tid >> 3) & 3)) * 8; // swizzled source quad (u16)
    u16* AsW = As + wave * 512;                         // wave-uniform LDS base
    u16* BsW = Bs + wave * 512;

    const u16* bsrc0 = w1t + ((size_t)e * F_HID + n0 + srow) * D_EMB + skq;
    const u16* bsrc1 = bsrc0 + (size_t)64 * D_EMB;

    for (int m0 = blockIdx.y * 128; m0 < Cl; m0 += gridDim.y * 128) {
        int pr0 = lo + m0 + srow;
        int tok0 = (m0 + srow < Cl) ? plist[pr0] : 0;
        int tok1 = (m0 + 64 + srow < Cl) ? plist[pr0 + 64] : 0;
        const u16* asrc0 = xb + (size_t)tok0 * D_EMB + skq;
        const u16* asrc1 = xb + (size_t)tok1 * D_EMB + skq;
        f32x4 acc[4][4] = {};
        for (int k0 = 0; k0 < D_EMB; k0 += 32) {
            gll16(asrc0 + k0, AsW);
            gll16(asrc1 + k0, AsW + 2048);
            gll16(bsrc0 + k0, BsW);
            gll16(bsrc1 + k0, BsW + 2048);
            __syncthreads();
            bfrag af[4], bf[4];
#pragma unroll
            for (int i = 0; i < 4; i++) {
                af[i] = *(const bfrag*)(&As[(wr * 64 + i * 16 + r) * 32 + qa]);
                bf[i] = *(const bfrag*)(&Bs[(wc * 64 + i * 16 + r) * 32 + qa]);
            }
#pragma unroll
            for (int mi = 0; mi < 4; mi++)
#pragma unroll
                for (int ni = 0; ni < 4; ni++)
                    acc[mi][ni] = mfma16(af[mi], bf[ni], acc[mi][ni]);
            __syncthreads();
        }
#pragma unroll
        for (int mi = 0; mi < 4; mi++)
#pragma unroll
            for (int ni = 0; ni < 4; ni++) {
                int col = n0 + wc * 64 + ni * 16 + r;
                float bias = b1[(size_t)e * F_HID + col];
#pragma unroll
                for (int i = 0; i < 4; i++) {
                    int m = m0 + wr * 64 + mi * 16 + q * 4 + i;
                    if (m < Cl) {
                        float v = acc[mi][ni][i] + bias;
                        h[(size_t)(lo - P0 + m) * F_HID + col] = f2b(v > 0.f ? v : 0.f);
                    }
                }
            }
    }
}

// ---------------------------------------------------------------- FFN2 GEMM
// y[p] = h[p-P0] . w2t[e]^T + b2[e]  (plain stores, no atomics, no split-K)
// 64x128x32 tiles, 4 waves (2M x 2N), each wave 32x64 (acc[2][4]).
__global__ __launch_bounds__(256) void moe_ffn2_kernel(
    const u16* __restrict__ h, const u16* __restrict__ w2t, const float* __restrict__ b2,
    const int* __restrict__ cnt, const int* __restrict__ off,
    float* __restrict__ y, int P0, int P1)
{
    __shared__ __align__(16) u16 As[64 * 32];
    __shared__ __align__(16) u16 Bs[128 * 32];
    const int e = blockIdx.z;
    int lo = off[e], hi = lo + cnt[e];
    if (lo < P0) lo = P0;
    if (hi > P1) hi = P1;
    const int Cl = hi - lo;
    if (Cl <= 0) return;
    const int n0 = blockIdx.x * 128;
    const int tid = threadIdx.x;
    const int lane = tid & 63, wave = tid >> 6;
    const int wr = wave >> 1, wc = wave & 1;
    const int q = lane >> 4, r = lane & 15;
    const int qa = (q ^ ((r >> 1) & 3)) * 8;
    const int srow = tid >> 2;                          // 0..63
    const int skq = ((tid & 3) ^ ((tid >> 3) & 3)) * 8;
    u16* AsW = As + wave * 512;
    u16* BsW = Bs + wave * 512;
    const int hcap = P1 - P0;

    const u16* bsrc0 = w2t + ((size_t)e * D_EMB + n0 + srow) * F_HID + skq;
    const u16* bsrc1 = bsrc0 + (size_t)64 * F_HID;

    for (int m0 = blockIdx.y * 64; m0 < Cl; m0 += gridDim.y * 64) {
        int hr = lo - P0 + m0 + srow;
        if (hr >= hcap) hr = hcap - 1;                  // clamped rows are masked at store
        const u16* asrc = h + (size_t)hr * F_HID + skq;
        f32x4 acc[2][4] = {};
        for (int k0 = 0; k0 < F_HID; k0 += 32) {
            gll16(asrc + k0, AsW);
            gll16(bsrc0 + k0, BsW);
            gll16(bsrc1 + k0, BsW + 2048);
            __syncthreads();
            bfrag af[2], bf[4];
#pragma unroll
            for (int i = 0; i < 2; i++)
                af[i] = *(const bfrag*)(&As[(wr * 32 + i * 16 + r) * 32 + qa]);
#pragma unroll
            for (int i = 0; i < 4; i++)
                bf[i] = *(const bfrag*)(&Bs[(wc * 64 + i * 16 + r) * 32 + qa]);
#pragma unroll
            for (int mi = 0; mi < 2; mi++)
#pragma unroll
                for (int ni = 0; ni < 4; ni++)
                    acc[mi][ni] = mfma16(af[mi], bf[ni], acc[mi][ni]);
            __syncthreads();
        }
#pragma unroll
        for (int mi = 0; mi < 2; mi++)
#pragma unroll
            for (int ni = 0; ni < 4; ni++) {
                int col = n0 + wc * 64 + ni * 16 + r;
                float bias = b2[(size_t)e * D_EMB + col];
#pragma unroll
                for (int i = 0; i < 4; i++) {
                    int m = m0 + wr * 32 + mi * 16 + q * 4 + i;
                    if (m < Cl)
                        y[(size_t)(lo + m) * D_EMB + col] = acc[mi][ni][i] + bias;
                }
            }
    }
}

// ---------------------------------------------------------------- combine
// out[t] = sum_k gate[t,k] * y[pos[t,k]]  (writes every token -> no zero pass)
__global__ __launch_bounds__(256) void moe_combine_kernel(
    const float* __restrict__ y, const int* __restrict__ tk_e,
    const float* __restrict__ tk_g, const int* __restrict__ pos,
    float4* __restrict__ out)
{
    int i = blockIdx.x * 256 + threadIdx.x;   // 786432 float4
    int t = i / 192;
    int c = i - t * 192;
    float4 a = make_float4(0.f, 0.f, 0.f, 0.f);
#pragma unroll
    for (int k = 0; k < 2; k++) {
        int e = tk_e[t * 2 + k];
        if (e >= 0) {
            float g = tk_g[t * 2 + k];
            float4 v = ((const float4*)(y + (size_t)pos[t * 2 + k] * D_EMB))[c];
            a.x += g * v.x; a.y += g * v.y; a.z += g * v.z; a.w += g * v.w;
        }
    }
    out[i] = a;
}

// ---------------------------------------------------------------- fallback fused FFN (fp32)
#define XSTR 776
#define HSTR 3080
#define BMF 8
__global__ __launch_bounds__(256) void moe_ffn_fused_f32(
    const float* __restrict__ x,
    const float* __restrict__ w1, const float* __restrict__ b1,
    const float* __restrict__ w2, const float* __restrict__ b2,
    const int* __restrict__ plist, const float* __restrict__ pg,
    const int* __restrict__ cnt, const int* __restrict__ off,
    float* __restrict__ out)
{
    __shared__ __align__(16) u16 xs[BMF * XSTR];
    __shared__ __align__(16) u16 hs[BMF * HSTR];
    const int e = blockIdx.x;
    const int Cl = cnt[e];
    if (Cl <= 0) return;
    const int O = off[e];
    const int tid = threadIdx.x;
    for (int t0 = blockIdx.y * BMF; t0 < Cl; t0 += gridDim.y * BMF) {
        for (int ci = tid; ci < BMF * 192; ci += 256) {
            int row = ci / 192, c = ci - row * 192;
            float4 v = make_float4(0.f, 0.f, 0.f, 0.f);
            if (t0 + row < Cl) {
                int tok = plist[O + t0 + row];
                v = *(const float4*)(x + (size_t)tok * D_EMB + c * 4);
            }
            u16* d = &xs[row * XSTR + c * 4];
            d[0] = f2b(v.x); d[1] = f2b(v.y); d[2] = f2b(v.z); d[3] = f2b(v.w);
        }
        __syncthreads();
        for (int wi = tid; wi < BMF * 768; wi += 256) {
            int row = wi / 768, nc = wi - row * 768;
            int n0 = nc * 4;
            float a0 = 0, a1 = 0, a2 = 0, a3 = 0;
            const float* wp = w1 + (size_t)e * D_EMB * F_HID + n0;
            const u16* xr = &xs[row * XSTR];
            for (int k = 0; k < D_EMB; k++) {
                float4 wv = *(const float4*)(wp + (size_t)k * F_HID);
                float xv = b2f(xr[k]);
                a0 += xv * wv.x; a1 += xv * wv.y; a2 += xv * wv.z; a3 += xv * wv.w;
            }
            const float* bp = b1 + (size_t)e * F_HID + n0;
            u16* hp = &hs[row * HSTR + n0];
            float v;
            v = a0 + bp[0]; hp[0] = f2b(v > 0.f ? v : 0.f);
            v = a1 + bp[1]; hp[1] = f2b(v > 0.f ? v : 0.f);
            v = a2 + bp[2]; hp[2] = f2b(v > 0.f ? v : 0.f);
            v = a3 + bp[3]; hp[3] = f2b(v > 0.f ? v : 0.f);
        }
        __syncthreads();
        for (int wi = tid; wi < BMF * 192; wi += 256) {
            int row = wi / 192, nc = wi - row * 192;
            int n0 = nc * 4;
            float a0 = 0, a1 = 0, a2 = 0, a3 = 0;
            const float* wp = w2 + (size_t)e * F_HID * D_EMB + n0;
            const u16* hr = &hs[row * HSTR];
            for (int k = 0; k < F_HID; k++) {
                float4 wv = *(const float4*)(wp + (size_t)k * D_EMB);
                float hv = b2f(hr[k]);
                a0 += hv * wv.x; a1 += hv * wv.y; a2 += hv * wv.z; a3 += hv * wv.w;
            }
            if (t0 + row < Cl) {
                int p = O + t0 + row;
                int tok = plist[p];
                float g = pg[p];
                const float* bp = b2 + (size_t)e * D_EMB + n0;
                float* op = out + (size_t)tok * D_EMB + n0;
                atomicAdd(&op[0], g * (a0 + bp[0]));
                atomicAdd(&op[1], g * (a1 + bp[1]));
                atomicAdd(&op[2], g * (a2 + bp[2]));
                atomicAdd(&op[3], g * (a3 + bp[3]));
            }
        }
        __syncthreads();
    }
}

// ---------------------------------------------------------------- launch
extern "C" void kernel_launch(void* const* d_in, const int* in_sizes, int n_in,
                              void* d_out, int out_size, void* d_ws, size_t ws_size,
                              hipStream_t stream) {
    const float* x     = (const float*)d_in[0];
    const float* noise = (const float*)d_in[1];
    const float* Wg    = (const float*)d_in[2];
    const float* bg    = (const float*)d_in[3];
    const float* Wn    = (const float*)d_in[4];
    const float* bn    = (const float*)d_in[5];
    const float* W1    = (const float*)d_in[6];
    const float* b1    = (const float*)d_in[7];
    const float* W2    = (const float*)d_in[8];
    const float* b2    = (const float*)d_in[9];
    float* out = (float*)d_out;

    // workspace layout
    char* ws = (char*)d_ws;
    int*   cnt    = (int*)(ws + 0);
    int*   off    = (int*)(ws + 256);
    int*   cursor = (int*)(ws + 512);
    int*   tk_e   = (int*)(ws + 1024);       // 32768 B
    float* tk_g   = (float*)(ws + 33792);    // 32768 B
    int*   plist  = (int*)(ws + 66560);      // 32768 B
    float* pg     = (float*)(ws + 99328);    // 32768 B
    int*   pos    = (int*)(ws + 132096);     // 32768 B
    const size_t W1T_OFF = 164864;                      // 8*3072*768*2 = 37748736
    const size_t W2T_OFF = W1T_OFF + 37748736ull;
    const size_t XB_OFF  = W2T_OFF + 37748736ull;       // xb: 4096*768*2 = 6291456
    const size_t Y_OFF   = XB_OFF + 6291456ull;         // y: 8192*768*4 = 25165824
    const size_t H_OFF   = Y_OFF + 25165824ull;         // h: pchunk*3072*2
    u16*   w1t = (u16*)(ws + W1T_OFF);
    u16*   w2t = (u16*)(ws + W2T_OFF);
    u16*   xb  = (u16*)(ws + XB_OFF);
    float* y   = (float*)(ws + Y_OFF);
    u16*   h   = (u16*)(ws + H_OFF);

    // largest h chunk that fits (0 => fallback path). Depends only on ws_size.
    int pchunk = 0;
    for (int p = N_PAIR; p >= 512; p >>= 1) {
        if (H_OFF + (size_t)p * F_HID * 2 <= ws_size) { pchunk = p; break; }
    }

    moe_init_kernel<<<dim3(1), dim3(64), 0, stream>>>(cnt);
    moe_router_f32<<<dim3(N_TOK / 4), dim3(256), 0, stream>>>(
        x, noise, Wg, bg, Wn, bn, tk_e, tk_g, cnt);
    moe_offsets_kernel<<<dim3(1), dim3(64), 0, stream>>>(cnt, off, cursor);
    moe_scatter_kernel<<<dim3(N_PAIR / 256), dim3(256), 0, stream>>>(
        tk_e, tk_g, cursor, plist, pg, pos);

    if (pchunk > 0) {
        // fast path: MFMA grouped GEMMs, global_load_lds staging, no atomics
        moe_cvtx_kernel<<<dim3(3072), dim3(256), 0, stream>>>(
            (const float4*)x, (ushort4*)xb);
        moe_transcvt_kernel<<<dim3(F_HID / 32, D_EMB / 32, 8), dim3(256), 0, stream>>>(
            W1, w1t, D_EMB, F_HID);   // [e][768][3072] -> [e][3072][768]
        moe_transcvt_kernel<<<dim3(D_EMB / 32, F_HID / 32, 8), dim3(256), 0, stream>>>(
            W2, w2t, F_HID, D_EMB);   // [e][3072][768] -> [e][768][3072]
        for (int c = 0; c < N_PAIR / pchunk; c++) {
            int P0 = c * pchunk, P1 = P0 + pchunk;
            moe_ffn1_kernel<<<dim3(F_HID / 128, 16, 8), dim3(256), 0, stream>>>(
                xb, w1t, b1, plist, cnt, off, h, P0, P1);
            moe_ffn2_kernel<<<dim3(D_EMB / 128, 32, 8), dim3(256), 0, stream>>>(
                h, w2t, b2, cnt, off, y, P0, P1);
        }
        moe_combine_kernel<<<dim3(3072), dim3(256), 0, stream>>>(
            y, tk_e, tk_g, pos, (float4*)out);
    } else {
        moe_zero_kernel<<<dim3(3072), dim3(256), 0, stream>>>((uint4*)out);
        moe_ffn_fused_f32<<<dim3(8, 192), dim3(256), 0, stream>>>(
            x, W1, b1, W2, b2, plist, pg, cnt, off, out);
    }
    (void)in_sizes; (void)n_in; (void)out_size;
}

// Round 2
// 519.803 us; speedup vs baseline: 1.1614x; 1.0322x over previous
//
#include <hip/hip_runtime.h>
#include <math.h>

typedef unsigned short u16;
typedef unsigned int u32;

#define D_EMB 768
#define F_HID 3072
#define N_TOK 4096
#define N_PAIR 8192
#define GATE_TH 1e-9f

typedef float f32x4 __attribute__((ext_vector_type(4)));
typedef __bf16 bfrag __attribute__((ext_vector_type(8)));

__device__ inline float b2f(u16 u) {
    union { float f; u32 i; } c; c.i = ((u32)u) << 16; return c.f;
}
__device__ inline u16 f2b(float f) {
    union { float f; u32 i; } c; c.f = f;
    u32 r = c.i + 0x7FFFu + ((c.i >> 16) & 1u);   // round-nearest-even
    return (u16)(r >> 16);
}
__device__ inline f32x4 mfma16(bfrag a, bfrag b, f32x4 c) {
    return __builtin_amdgcn_mfma_f32_16x16x32_bf16(a, b, c, 0, 0, 0);
}
// async global->LDS, 16B per lane. LDS dest = wave-uniform base + lane*16.
__device__ inline void gll16(const u16* g, u16* l) {
    __builtin_amdgcn_global_load_lds(
        (const __attribute__((address_space(1))) u32*)g,
        (__attribute__((address_space(3))) u32*)l, 16, 0, 0);
}
__device__ inline void sbar() {
    asm volatile("" ::: "memory");
    __builtin_amdgcn_s_barrier();
    asm volatile("" ::: "memory");
}
__device__ inline void waitv0() { asm volatile("s_waitcnt vmcnt(0)" ::: "memory"); }

// ---------------------------------------------------------------- init / zero
__global__ void moe_init_kernel(int* __restrict__ cnt) {
    if (threadIdx.x < 8) cnt[threadIdx.x] = 0;
}
__global__ __launch_bounds__(256) void moe_zero_kernel(uint4* __restrict__ out) {
    int i = blockIdx.x * 256 + threadIdx.x;   // 786432 uint4 = 12.58 MB (fp32 out)
    out[i] = make_uint4(0, 0, 0, 0);
}

// ---------------------------------------------------------------- router (fp32)
__global__ __launch_bounds__(256) void moe_router_f32(
    const float* __restrict__ x, const float* __restrict__ noise,
    const float* __restrict__ Wg, const float* __restrict__ bg,
    const float* __restrict__ Wn, const float* __restrict__ bn,
    int* __restrict__ tk_e, float* __restrict__ tk_g, int* __restrict__ cnt)
{
    const int t = blockIdx.x * 4 + (threadIdx.x >> 6);
    const int lane = threadIdx.x & 63;
    float ag[8] = {}, an[8] = {};
    for (int i = 0; i < 12; i++) {
        int k = i * 64 + lane;
        float xv = x[(size_t)t * D_EMB + k];
        const float* wgp = Wg + k * 8;
        const float* wnp = Wn + k * 8;
#pragma unroll
        for (int e = 0; e < 8; e++) {
            ag[e] += xv * wgp[e];
            an[e] += xv * wnp[e];
        }
    }
#pragma unroll
    for (int e = 0; e < 8; e++) {
        float vg = ag[e], vn = an[e];
        for (int s = 32; s; s >>= 1) { vg += __shfl_xor(vg, s); vn += __shfl_xor(vn, s); }
        ag[e] = vg; an[e] = vn;
    }
    if (lane == 0) {
        float best = -INFINITY, sec = -INFINITY; int be = 0, se = 0;
#pragma unroll
        for (int e = 0; e < 8; e++) {
            float nl = an[e] + bn[e];
            float sp = nl > 0.f ? nl + log1pf(expf(-nl)) : log1pf(expf(nl));  // softplus
            float v = ag[e] + bg[e] + noise[(size_t)t * 8 + e] * sp;
            if (v > best) { sec = best; se = be; best = v; be = e; }
            else if (v > sec) { sec = v; se = e; }
        }
        float ex = expf(sec - best);
        float g1 = 1.f / (1.f + ex), g2 = ex / (1.f + ex);
        tk_e[t * 2 + 0] = (g1 > GATE_TH) ? be : -1; tk_g[t * 2 + 0] = g1;
        tk_e[t * 2 + 1] = (g2 > GATE_TH) ? se : -1; tk_g[t * 2 + 1] = g2;
        if (g1 > GATE_TH) atomicAdd(&cnt[be], 1);
        if (g2 > GATE_TH) atomicAdd(&cnt[se], 1);
    }
}

// ---------------------------------------------------------------- offsets / scatter
__global__ void moe_offsets_kernel(const int* __restrict__ cnt,
                                   int* __restrict__ off, int* __restrict__ cursor) {
    if (threadIdx.x == 0) {
        int s = 0;
        for (int e = 0; e < 8; e++) { off[e] = s; cursor[e] = s; s += cnt[e]; }
    }
}
__global__ void moe_scatter_kernel(const int* __restrict__ tk_e, const float* __restrict__ tk_g,
                                   int* __restrict__ cursor, int* __restrict__ plist,
                                   float* __restrict__ pg, int* __restrict__ pos) {
    int i = blockIdx.x * 256 + threadIdx.x;
    if (i < N_PAIR) {
        int e = tk_e[i];
        if (e >= 0) {
            int p = atomicAdd(&cursor[e], 1);
            plist[p] = i >> 1;
            pg[p] = tk_g[i];
            pos[i] = p;
        }
    }
}

// ---------------------------------------------------------------- x -> bf16
__global__ __launch_bounds__(256) void moe_cvtx_kernel(
    const float4* __restrict__ x, ushort4* __restrict__ xb) {
    int i = blockIdx.x * 256 + threadIdx.x;   // 786432
    float4 v = x[i];
    ushort4 o;
    o.x = f2b(v.x); o.y = f2b(v.y); o.z = f2b(v.z); o.w = f2b(v.w);
    xb[i] = o;
}

// ---------------------------------------------------------------- transpose+convert
// in fp32 [Z][R][C] -> out bf16 [Z][C][R]
__global__ __launch_bounds__(256) void moe_transcvt_kernel(
    const float* __restrict__ in, u16* __restrict__ out, int R, int C) {
    __shared__ float tile[32][33];
    const int z = blockIdx.z;
    const int c0 = blockIdx.x * 32, r0 = blockIdx.y * 32;
    const int tx = threadIdx.x & 31, ty = threadIdx.x >> 5;   // ty 0..7
    const size_t base = (size_t)z * R * C;
#pragma unroll
    for (int j = 0; j < 32; j += 8)
        tile[ty + j][tx] = in[base + (size_t)(r0 + ty + j) * C + c0 + tx];
    __syncthreads();
#pragma unroll
    for (int j = 0; j < 32; j += 8)
        out[base + (size_t)(c0 + ty + j) * R + r0 + tx] = f2b(tile[tx][ty + j]);
}

// ---------------------------------------------------------------- FFN1 GEMM
// h[p-P0] = relu(xb[plist[p]] . w1t[e]^T + b1[e])
// 128x128 tile, BK=64, double-buffered LDS, global_load_lds staging with
// source-side XOR swizzle (slot ^= row&7 over 8x16B slots per 128B row),
// 2-phase prefetch pipeline (stage next tile, compute, vmcnt(0)+barrier).
// XCD-chunked block swizzle: one expert per XCD, n fastest.
__global__ __launch_bounds__(256) void moe_ffn1_kernel(
    const u16* __restrict__ xb, const u16* __restrict__ w1t, const float* __restrict__ b1,
    const int* __restrict__ plist, const int* __restrict__ cnt, const int* __restrict__ off,
    u16* __restrict__ h, int P0, int P1)
{
    __shared__ __align__(16) u16 As[2][128 * 64];   // 2 x 16 KB
    __shared__ __align__(16) u16 Bs[2][128 * 64];   // 2 x 16 KB
    const int GX = 24, GY = 16;                     // grid = (24,16,8), nwg=3072
    int f = blockIdx.x + GX * (blockIdx.y + GY * blockIdx.z);
    int swz = (f & 7) * 384 + (f >> 3);             // bijective, chunk=384=one expert
    int nb = swz % GX;
    int t2 = swz / GX;
    int mb = t2 % GY;
    int e  = t2 / GY;

    int lo = off[e], hi = lo + cnt[e];
    if (lo < P0) lo = P0;
    if (hi > P1) hi = P1;
    const int Cl = hi - lo;
    if (Cl <= 0) return;
    const int n0 = nb * 128;
    const int tid = threadIdx.x;
    const int lane = tid & 63, wave = tid >> 6;
    const int wr = wave >> 1, wc = wave & 1;
    const int qq = lane >> 4, r = lane & 15;
    const int srow = tid >> 3;                      // 0..31 (row within 32-row round)
    const int gq = (tid & 7) ^ (srow & 7);          // swizzled source 16B-slot

    const u16* bsrc[4];
#pragma unroll
    for (int j = 0; j < 4; j++)
        bsrc[j] = w1t + ((size_t)e * F_HID + n0 + j * 32 + srow) * D_EMB + gq * 8;

    for (int m0 = mb * 128; m0 < Cl; m0 += GY * 128) {
        const u16* asrc[4];
#pragma unroll
        for (int j = 0; j < 4; j++) {
            int mr = m0 + j * 32 + srow;
            if (mr > Cl - 1) mr = Cl - 1;
            asrc[j] = xb + (size_t)plist[lo + mr] * D_EMB + gq * 8;
        }
        f32x4 acc[4][4] = {};
        int cur = 0;
        // prologue: stage k-tile 0 into buf 0
#pragma unroll
        for (int j = 0; j < 4; j++) gll16(asrc[j], &As[0][j * 2048 + wave * 512]);
#pragma unroll
        for (int j = 0; j < 4; j++) gll16(bsrc[j], &Bs[0][j * 2048 + wave * 512]);
        waitv0(); sbar();
        for (int kt = 0; kt < 12; kt++) {
            if (kt < 11) {
                const int k0 = (kt + 1) * 64;
#pragma unroll
                for (int j = 0; j < 4; j++)
                    gll16(asrc[j] + k0, &As[cur ^ 1][j * 2048 + wave * 512]);
#pragma unroll
                for (int j = 0; j < 4; j++)
                    gll16(bsrc[j] + k0, &Bs[cur ^ 1][j * 2048 + wave * 512]);
            }
#pragma unroll
            for (int kk = 0; kk < 2; kk++) {
                bfrag af[4], bf[4];
#pragma unroll
                for (int i = 0; i < 4; i++) {
                    int rowa = wr * 64 + i * 16 + r;
                    int rowb = wc * 64 + i * 16 + r;
                    int slot = ((qq + 4 * kk) ^ (r & 7)) * 8;
                    af[i] = *(const bfrag*)(&As[cur][rowa * 64 + slot]);
                    bf[i] = *(const bfrag*)(&Bs[cur][rowb * 64 + slot]);
                }
#pragma unroll
                for (int mi = 0; mi < 4; mi++)
#pragma unroll
                    for (int ni = 0; ni < 4; ni++)
                        acc[mi][ni] = mfma16(af[mi], bf[ni], acc[mi][ni]);
            }
            waitv0(); sbar();
            cur ^= 1;
        }
#pragma unroll
        for (int mi = 0; mi < 4; mi++)
#pragma unroll
            for (int ni = 0; ni < 4; ni++) {
                int col = n0 + wc * 64 + ni * 16 + r;
                float bias = b1[(size_t)e * F_HID + col];
#pragma unroll
                for (int i = 0; i < 4; i++) {
                    int m = m0 + wr * 64 + mi * 16 + qq * 4 + i;
                    if (m < Cl) {
                        float v = acc[mi][ni][i] + bias;
                        h[(size_t)(lo - P0 + m) * F_HID + col] = f2b(v > 0.f ? v : 0.f);
                    }
                }
            }
    }
}

// ---------------------------------------------------------------- FFN2 GEMM
// y[p] = h[p-P0] . w2t[e]^T + b2[e]  (plain stores, no atomics)
// 64x128 tile, BK=64, dbuf + 2-phase prefetch, same swizzles as ffn1.
__global__ __launch_bounds__(256) void moe_ffn2_kernel(
    const u16* __restrict__ h, const u16* __restrict__ w2t, const float* __restrict__ b2,
    const int* __restrict__ cnt, const int* __restrict__ off,
    float* __restrict__ y, int P0, int P1)
{
    __shared__ __align__(16) u16 As[2][64 * 64];    // 2 x 8 KB
    __shared__ __align__(16) u16 Bs[2][128 * 64];   // 2 x 16 KB
    const int GX = 6, GY = 32;                      // grid = (6,32,8), nwg=1536
    int f = blockIdx.x + GX * (blockIdx.y + GY * blockIdx.z);
    int swz = (f & 7) * 192 + (f >> 3);             // chunk=192=one expert
    int nb = swz % GX;
    int t2 = swz / GX;
    int mb = t2 % GY;
    int e  = t2 / GY;

    int lo = off[e], hi = lo + cnt[e];
    if (lo < P0) lo = P0;
    if (hi > P1) hi = P1;
    const int Cl = hi - lo;
    if (Cl <= 0) return;
    const int n0 = nb * 128;
    const int tid = threadIdx.x;
    const int lane = tid & 63, wave = tid >> 6;
    const int wr = wave >> 1, wc = wave & 1;
    const int qq = lane >> 4, r = lane & 15;
    const int srow = tid >> 3;
    const int gq = (tid & 7) ^ (srow & 7);

    const u16* bsrc[4];
#pragma unroll
    for (int j = 0; j < 4; j++)
        bsrc[j] = w2t + ((size_t)e * D_EMB + n0 + j * 32 + srow) * F_HID + gq * 8;

    for (int m0 = mb * 64; m0 < Cl; m0 += GY * 64) {
        const u16* asrc[2];
#pragma unroll
        for (int j = 0; j < 2; j++) {
            int mr = m0 + j * 32 + srow;
            if (mr > Cl - 1) mr = Cl - 1;
            asrc[j] = h + (size_t)(lo - P0 + mr) * F_HID + gq * 8;
        }
        f32x4 acc[2][4] = {};
        int cur = 0;
#pragma unroll
        for (int j = 0; j < 2; j++) gll16(asrc[j], &As[0][j * 2048 + wave * 512]);
#pragma unroll
        for (int j = 0; j < 4; j++) gll16(bsrc[j], &Bs[0][j * 2048 + wave * 512]);
        waitv0(); sbar();
        for (int kt = 0; kt < 48; kt++) {
            if (kt < 47) {
                const int k0 = (kt + 1) * 64;
#pragma unroll
                for (int j = 0; j < 2; j++)
                    gll16(asrc[j] + k0, &As[cur ^ 1][j * 2048 + wave * 512]);
#pragma unroll
                for (int j = 0; j < 4; j++)
                    gll16(bsrc[j] + k0, &Bs[cur ^ 1][j * 2048 + wave * 512]);
            }
#pragma unroll
            for (int kk = 0; kk < 2; kk++) {
                bfrag af[2], bf[4];
#pragma unroll
                for (int i = 0; i < 2; i++) {
                    int rowa = wr * 32 + i * 16 + r;
                    int slot = ((qq + 4 * kk) ^ (r & 7)) * 8;
                    af[i] = *(const bfrag*)(&As[cur][rowa * 64 + slot]);
                }
#pragma unroll
                for (int i = 0; i < 4; i++) {
                    int rowb = wc * 64 + i * 16 + r;
                    int slot = ((qq + 4 * kk) ^ (r & 7)) * 8;
                    bf[i] = *(const bfrag*)(&Bs[cur][rowb * 64 + slot]);
                }
#pragma unroll
                for (int mi = 0; mi < 2; mi++)
#pragma unroll
                    for (int ni = 0; ni < 4; ni++)
                        acc[mi][ni] = mfma16(af[mi], bf[ni], acc[mi][ni]);
            }
            waitv0(); sbar();
            cur ^= 1;
        }
#pragma unroll
        for (int mi = 0; mi < 2; mi++)
#pragma unroll
            for (int ni = 0; ni < 4; ni++) {
                int col = n0 + wc * 64 + ni * 16 + r;
                float bias = b2[(size_t)e * D_EMB + col];
#pragma unroll
                for (int i = 0; i < 4; i++) {
                    int m = m0 + wr * 32 + mi * 16 + qq * 4 + i;
                    if (m < Cl)
                        y[(size_t)(lo + m) * D_EMB + col] = acc[mi][ni][i] + bias;
                }
            }
    }
}

// ---------------------------------------------------------------- combine
// out[t] = sum_k gate[t,k] * y[pos[t,k]]  (writes every token -> no zero pass)
__global__ __launch_bounds__(256) void moe_combine_kernel(
    const float* __restrict__ y, const int* __restrict__ tk_e,
    const float* __restrict__ tk_g, const int* __restrict__ pos,
    float4* __restrict__ out)
{
    int i = blockIdx.x * 256 + threadIdx.x;   // 786432 float4
    int t = i / 192;
    int c = i - t * 192;
    float4 a = make_float4(0.f, 0.f, 0.f, 0.f);
#pragma unroll
    for (int k = 0; k < 2; k++) {
        int e = tk_e[t * 2 + k];
        if (e >= 0) {
            float g = tk_g[t * 2 + k];
            float4 v = ((const float4*)(y + (size_t)pos[t * 2 + k] * D_EMB))[c];
            a.x += g * v.x; a.y += g * v.y; a.z += g * v.z; a.w += g * v.w;
        }
    }
    out[i] = a;
}

// ---------------------------------------------------------------- fallback fused FFN (fp32)
#define XSTR 776
#define HSTR 3080
#define BMF 8
__global__ __launch_bounds__(256) void moe_ffn_fused_f32(
    const float* __restrict__ x,
    const float* __restrict__ w1, const float* __restrict__ b1,
    const float* __restrict__ w2, const float* __restrict__ b2,
    const int* __restrict__ plist, const float* __restrict__ pg,
    const int* __restrict__ cnt, const int* __restrict__ off,
    float* __restrict__ out)
{
    __shared__ __align__(16) u16 xs[BMF * XSTR];
    __shared__ __align__(16) u16 hs[BMF * HSTR];
    const int e = blockIdx.x;
    const int Cl = cnt[e];
    if (Cl <= 0) return;
    const int O = off[e];
    const int tid = threadIdx.x;
    for (int t0 = blockIdx.y * BMF; t0 < Cl; t0 += gridDim.y * BMF) {
        for (int ci = tid; ci < BMF * 192; ci += 256) {
            int row = ci / 192, c = ci - row * 192;
            float4 v = make_float4(0.f, 0.f, 0.f, 0.f);
            if (t0 + row < Cl) {
                int tok = plist[O + t0 + row];
                v = *(const float4*)(x + (size_t)tok * D_EMB + c * 4);
            }
            u16* d = &xs[row * XSTR + c * 4];
            d[0] = f2b(v.x); d[1] = f2b(v.y); d[2] = f2b(v.z); d[3] = f2b(v.w);
        }
        __syncthreads();
        for (int wi = tid; wi < BMF * 768; wi += 256) {
            int row = wi / 768, nc = wi - row * 768;
            int n0 = nc * 4;
            float a0 = 0, a1 = 0, a2 = 0, a3 = 0;
            const float* wp = w1 + (size_t)e * D_EMB * F_HID + n0;
            const u16* xr = &xs[row * XSTR];
            for (int k = 0; k < D_EMB; k++) {
                float4 wv = *(const float4*)(wp + (size_t)k * F_HID);
                float xv = b2f(xr[k]);
                a0 += xv * wv.x; a1 += xv * wv.y; a2 += xv * wv.z; a3 += xv * wv.w;
            }
            const float* bp = b1 + (size_t)e * F_HID + n0;
            u16* hp = &hs[row * HSTR + n0];
            float v;
            v = a0 + bp[0]; hp[0] = f2b(v > 0.f ? v : 0.f);
            v = a1 + bp[1]; hp[1] = f2b(v > 0.f ? v : 0.f);
            v = a2 + bp[2]; hp[2] = f2b(v > 0.f ? v : 0.f);
            v = a3 + bp[3]; hp[3] = f2b(v > 0.f ? v : 0.f);
        }
        __syncthreads();
        for (int wi = tid; wi < BMF * 192; wi += 256) {
            int row = wi / 192, nc = wi - row * 192;
            int n0 = nc * 4;
            float a0 = 0, a1 = 0, a2 = 0, a3 = 0;
            const float* wp = w2 + (size_t)e * F_HID * D_EMB + n0;
            const u16* hr = &hs[row * HSTR];
            for (int k = 0; k < F_HID; k++) {
                float4 wv = *(const float4*)(wp + (size_t)k * D_EMB);
                float hv = b2f(hr[k]);
                a0 += hv * wv.x; a1 += hv * wv.y; a2 += hv * wv.z; a3 += hv * wv.w;
            }
            if (t0 + row < Cl) {
                int p = O + t0 + row;
                int tok = plist[p];
                float g = pg[p];
                const float* bp = b2 + (size_t)e * D_EMB + n0;
                float* op = out + (size_t)tok * D_EMB + n0;
                atomicAdd(&op[0], g * (a0 + bp[0]));
                atomicAdd(&op[1], g * (a1 + bp[1]));
                atomicAdd(&op[2], g * (a2 + bp[2]));
                atomicAdd(&op[3], g * (a3 + bp[3]));
            }
        }
        __syncthreads();
    }
}

// ---------------------------------------------------------------- launch
extern "C" void kernel_launch(void* const* d_in, const int* in_sizes, int n_in,
                              void* d_out, int out_size, void* d_ws, size_t ws_size,
                              hipStream_t stream) {
    const float* x     = (const float*)d_in[0];
    const float* noise = (const float*)d_in[1];
    const float* Wg    = (const float*)d_in[2];
    const float* bg    = (const float*)d_in[3];
    const float* Wn    = (const float*)d_in[4];
    const float* bn    = (const float*)d_in[5];
    const float* W1    = (const float*)d_in[6];
    const float* b1    = (const float*)d_in[7];
    const float* W2    = (const float*)d_in[8];
    const float* b2    = (const float*)d_in[9];
    float* out = (float*)d_out;

    // workspace layout
    char* ws = (char*)d_ws;
    int*   cnt    = (int*)(ws + 0);
    int*   off    = (int*)(ws + 256);
    int*   cursor = (int*)(ws + 512);
    int*   tk_e   = (int*)(ws + 1024);       // 32768 B
    float* tk_g   = (float*)(ws + 33792);    // 32768 B
    int*   plist  = (int*)(ws + 66560);      // 32768 B
    float* pg     = (float*)(ws + 99328);    // 32768 B
    int*   pos    = (int*)(ws + 132096);     // 32768 B
    const size_t W1T_OFF = 164864;                      // 8*3072*768*2 = 37748736
    const size_t W2T_OFF = W1T_OFF + 37748736ull;
    const size_t XB_OFF  = W2T_OFF + 37748736ull;       // xb: 4096*768*2 = 6291456
    const size_t Y_OFF   = XB_OFF + 6291456ull;         // y: 8192*768*4 = 25165824
    const size_t H_OFF   = Y_OFF + 25165824ull;         // h: pchunk*3072*2
    u16*   w1t = (u16*)(ws + W1T_OFF);
    u16*   w2t = (u16*)(ws + W2T_OFF);
    u16*   xb  = (u16*)(ws + XB_OFF);
    float* y   = (float*)(ws + Y_OFF);
    u16*   h   = (u16*)(ws + H_OFF);

    // largest h chunk that fits (0 => fallback path). Depends only on ws_size.
    int pchunk = 0;
    for (int p = N_PAIR; p >= 512; p >>= 1) {
        if (H_OFF + (size_t)p * F_HID * 2 <= ws_size) { pchunk = p; break; }
    }

    moe_init_kernel<<<dim3(1), dim3(64), 0, stream>>>(cnt);
    moe_router_f32<<<dim3(N_TOK / 4), dim3(256), 0, stream>>>(
        x, noise, Wg, bg, Wn, bn, tk_e, tk_g, cnt);
    moe_offsets_kernel<<<dim3(1), dim3(64), 0, stream>>>(cnt, off, cursor);
    moe_scatter_kernel<<<dim3(N_PAIR / 256), dim3(256), 0, stream>>>(
        tk_e, tk_g, cursor, plist, pg, pos);

    if (pchunk > 0) {
        // fast path: MFMA grouped GEMMs, pipelined global_load_lds staging
        moe_cvtx_kernel<<<dim3(3072), dim3(256), 0, stream>>>(
            (const float4*)x, (ushort4*)xb);
        moe_transcvt_kernel<<<dim3(F_HID / 32, D_EMB / 32, 8), dim3(256), 0, stream>>>(
            W1, w1t, D_EMB, F_HID);   // [e][768][3072] -> [e][3072][768]
        moe_transcvt_kernel<<<dim3(D_EMB / 32, F_HID / 32, 8), dim3(256), 0, stream>>>(
            W2, w2t, F_HID, D_EMB);   // [e][3072][768] -> [e][768][3072]
        for (int c = 0; c < N_PAIR / pchunk; c++) {
            int P0 = c * pchunk, P1 = P0 + pchunk;
            moe_ffn1_kernel<<<dim3(24, 16, 8), dim3(256), 0, stream>>>(
                xb, w1t, b1, plist, cnt, off, h, P0, P1);
            moe_ffn2_kernel<<<dim3(6, 32, 8), dim3(256), 0, stream>>>(
                h, w2t, b2, cnt, off, y, P0, P1);
        }
        moe_combine_kernel<<<dim3(3072), dim3(256), 0, stream>>>(
            y, tk_e, tk_g, pos, (float4*)out);
    } else {
        moe_zero_kernel<<<dim3(3072), dim3(256), 0, stream>>>((uint4*)out);
        moe_ffn_fused_f32<<<dim3(8, 192), dim3(256), 0, stream>>>(
            x, W1, b1, W2, b2, plist, pg, cnt, off, out);
    }
    (void)in_sizes; (void)n_in; (void)out_size;
}

// Round 3
// 462.882 us; speedup vs baseline: 1.3043x; 1.1230x over previous
//
#include <hip/hip_runtime.h>
#include <math.h>

typedef unsigned short u16;
typedef unsigned int u32;

#define D_EMB 768
#define F_HID 3072
#define N_TOK 4096
#define N_PAIR 8192
#define GATE_TH 1e-9f

typedef float f32x4 __attribute__((ext_vector_type(4)));
typedef __bf16 bfrag __attribute__((ext_vector_type(8)));

__device__ inline float b2f(u16 u) {
    union { float f; u32 i; } c; c.i = ((u32)u) << 16; return c.f;
}
__device__ inline u16 f2b(float f) {
    union { float f; u32 i; } c; c.f = f;
    u32 r = c.i + 0x7FFFu + ((c.i >> 16) & 1u);   // round-nearest-even
    return (u16)(r >> 16);
}
__device__ inline f32x4 mfma16(bfrag a, bfrag b, f32x4 c) {
    return __builtin_amdgcn_mfma_f32_16x16x32_bf16(a, b, c, 0, 0, 0);
}
// async global->LDS, 16B per lane. LDS dest = wave-uniform base + lane*16.
__device__ inline void gll16(const u16* g, u16* l) {
    __builtin_amdgcn_global_load_lds(
        (const __attribute__((address_space(1))) u32*)g,
        (__attribute__((address_space(3))) u32*)l, 16, 0, 0);
}
__device__ inline void sbar() {
    asm volatile("" ::: "memory");
    __builtin_amdgcn_s_barrier();
    asm volatile("" ::: "memory");
}
__device__ inline void waitv0() { asm volatile("s_waitcnt vmcnt(0)" ::: "memory"); }
__device__ inline void waitv6() { asm volatile("s_waitcnt vmcnt(6)" ::: "memory"); }
__device__ inline void waitv8() { asm volatile("s_waitcnt vmcnt(8)" ::: "memory"); }

// ---------------------------------------------------------------- init / zero
__global__ void moe_init_kernel(int* __restrict__ cnt) {
    if (threadIdx.x < 8) cnt[threadIdx.x] = 0;
}
__global__ __launch_bounds__(256) void moe_zero_kernel(uint4* __restrict__ out) {
    int i = blockIdx.x * 256 + threadIdx.x;   // 786432 uint4 = 12.58 MB (fp32 out)
    out[i] = make_uint4(0, 0, 0, 0);
}

// ---------------------------------------------------------------- router v2 (fp32)
// 1 wave per block, 8 tokens per wave: lane = (tl = lane&7 -> token,
// q = lane>>3 -> k-eighth of 96). Each lane accumulates all 16 logits over its
// 96 k's; 3-level shfl reduce; lanes 0..7 do per-token top-k in parallel.
__global__ __launch_bounds__(64) void moe_router_v2(
    const float* __restrict__ x, const float* __restrict__ noise,
    const float* __restrict__ Wg, const float* __restrict__ bg,
    const float* __restrict__ Wn, const float* __restrict__ bn,
    int* __restrict__ tk_e, float* __restrict__ tk_g, int* __restrict__ cnt)
{
    const int lane = threadIdx.x;
    const int tl = lane & 7, q = lane >> 3;
    const int t = blockIdx.x * 8 + tl;              // grid 512 -> 4096 tokens
    float ag[8] = {}, an[8] = {};
    const float4* xp = (const float4*)(x + (size_t)t * D_EMB + q * 96);
#pragma unroll 4
    for (int k4 = 0; k4 < 24; k4++) {
        float4 xv = xp[k4];
        const int kb = q * 96 + k4 * 4;
#pragma unroll
        for (int c = 0; c < 4; c++) {
            float xc = (&xv.x)[c];
            const float4* wg = (const float4*)(Wg + (size_t)(kb + c) * 8);
            const float4* wn = (const float4*)(Wn + (size_t)(kb + c) * 8);
            float4 g0 = wg[0], g1 = wg[1], n0 = wn[0], n1 = wn[1];
            ag[0] += xc * g0.x; ag[1] += xc * g0.y; ag[2] += xc * g0.z; ag[3] += xc * g0.w;
            ag[4] += xc * g1.x; ag[5] += xc * g1.y; ag[6] += xc * g1.z; ag[7] += xc * g1.w;
            an[0] += xc * n0.x; an[1] += xc * n0.y; an[2] += xc * n0.z; an[3] += xc * n0.w;
            an[4] += xc * n1.x; an[5] += xc * n1.y; an[6] += xc * n1.z; an[7] += xc * n1.w;
        }
    }
#pragma unroll
    for (int e = 0; e < 8; e++) {
        ag[e] += __shfl_xor(ag[e], 8);  an[e] += __shfl_xor(an[e], 8);
        ag[e] += __shfl_xor(ag[e], 16); an[e] += __shfl_xor(an[e], 16);
        ag[e] += __shfl_xor(ag[e], 32); an[e] += __shfl_xor(an[e], 32);
    }
    if (q == 0) {
        float best = -INFINITY, sec = -INFINITY; int be = 0, se = 0;
#pragma unroll
        for (int e = 0; e < 8; e++) {
            float nl = an[e] + bn[e];
            float sp = nl > 0.f ? nl + log1pf(expf(-nl)) : log1pf(expf(nl));  // softplus
            float v = ag[e] + bg[e] + noise[(size_t)t * 8 + e] * sp;
            if (v > best) { sec = best; se = be; best = v; be = e; }
            else if (v > sec) { sec = v; se = e; }
        }
        float ex = expf(sec - best);
        float g1 = 1.f / (1.f + ex), g2 = ex / (1.f + ex);
        tk_e[t * 2 + 0] = (g1 > GATE_TH) ? be : -1; tk_g[t * 2 + 0] = g1;
        tk_e[t * 2 + 1] = (g2 > GATE_TH) ? se : -1; tk_g[t * 2 + 1] = g2;
        if (g1 > GATE_TH) atomicAdd(&cnt[be], 1);
        if (g2 > GATE_TH) atomicAdd(&cnt[se], 1);
    }
}

// ---------------------------------------------------------------- offsets / scatter
__global__ void moe_offsets_kernel(const int* __restrict__ cnt,
                                   int* __restrict__ off, int* __restrict__ cursor) {
    if (threadIdx.x == 0) {
        int s = 0;
        for (int e = 0; e < 8; e++) { off[e] = s; cursor[e] = s; s += cnt[e]; }
    }
}
__global__ void moe_scatter_kernel(const int* __restrict__ tk_e, const float* __restrict__ tk_g,
                                   int* __restrict__ cursor, int* __restrict__ plist,
                                   float* __restrict__ pg, int* __restrict__ pos) {
    int i = blockIdx.x * 256 + threadIdx.x;
    if (i < N_PAIR) {
        int e = tk_e[i];
        if (e >= 0) {
            int p = atomicAdd(&cursor[e], 1);
            plist[p] = i >> 1;
            pg[p] = tk_g[i];
            pos[i] = p;
        }
    }
}

// ---------------------------------------------------------------- x -> bf16
__global__ __launch_bounds__(256) void moe_cvtx_kernel(
    const float4* __restrict__ x, ushort4* __restrict__ xb) {
    int i = blockIdx.x * 256 + threadIdx.x;   // 786432
    float4 v = x[i];
    ushort4 o;
    o.x = f2b(v.x); o.y = f2b(v.y); o.z = f2b(v.z); o.w = f2b(v.w);
    xb[i] = o;
}

// ---------------------------------------------------------------- transpose+convert
// in fp32 [Z][R][C] -> out bf16 [Z][C][R]
__global__ __launch_bounds__(256) void moe_transcvt_kernel(
    const float* __restrict__ in, u16* __restrict__ out, int R, int C) {
    __shared__ float tile[32][33];
    const int z = blockIdx.z;
    const int c0 = blockIdx.x * 32, r0 = blockIdx.y * 32;
    const int tx = threadIdx.x & 31, ty = threadIdx.x >> 5;   // ty 0..7
    const size_t base = (size_t)z * R * C;
#pragma unroll
    for (int j = 0; j < 32; j += 8)
        tile[ty + j][tx] = in[base + (size_t)(r0 + ty + j) * C + c0 + tx];
    __syncthreads();
#pragma unroll
    for (int j = 0; j < 32; j += 8)
        out[base + (size_t)(c0 + ty + j) * R + r0 + tx] = f2b(tile[tx][ty + j]);
}

// ---------------------------------------------------------------- FFN1 GEMM
// h[p-P0] = relu(xb[plist[p]] . w1t[e]^T + b1[e])
// 128x128 tile, BK=64, dbuf LDS, global_load_lds staging with source-side XOR
// swizzle, counted-vmcnt pipeline: next tile's loads stay in flight across
// both barriers and the compute (T4). XCD-chunked block swizzle.
__global__ __launch_bounds__(256) void moe_ffn1_kernel(
    const u16* __restrict__ xb, const u16* __restrict__ w1t, const float* __restrict__ b1,
    const int* __restrict__ plist, const int* __restrict__ cnt, const int* __restrict__ off,
    u16* __restrict__ h, int P0, int P1)
{
    __shared__ __align__(16) u16 As[2][128 * 64];   // 2 x 16 KB
    __shared__ __align__(16) u16 Bs[2][128 * 64];   // 2 x 16 KB
    const int GX = 24, GY = 16;                     // grid = (24,16,8), nwg=3072
    int f = blockIdx.x + GX * (blockIdx.y + GY * blockIdx.z);
    int swz = (f & 7) * 384 + (f >> 3);             // bijective, chunk=384=one expert
    int nb = swz % GX;
    int t2 = swz / GX;
    int mb = t2 % GY;
    int e  = t2 / GY;

    int lo = off[e], hi = lo + cnt[e];
    if (lo < P0) lo = P0;
    if (hi > P1) hi = P1;
    const int Cl = hi - lo;
    if (Cl <= 0) return;
    const int n0 = nb * 128;
    const int tid = threadIdx.x;
    const int lane = tid & 63, wave = tid >> 6;
    const int wr = wave >> 1, wc = wave & 1;
    const int qq = lane >> 4, r = lane & 15;
    const int srow = tid >> 3;                      // 0..31 (row within 32-row round)
    const int gq = (tid & 7) ^ (srow & 7);          // swizzled source 16B-slot

    const u16* bsrc[4];
#pragma unroll
    for (int j = 0; j < 4; j++)
        bsrc[j] = w1t + ((size_t)e * F_HID + n0 + j * 32 + srow) * D_EMB + gq * 8;

    for (int m0 = mb * 128; m0 < Cl; m0 += GY * 128) {
        const u16* asrc[4];
#pragma unroll
        for (int j = 0; j < 4; j++) {
            int mr = m0 + j * 32 + srow;
            if (mr > Cl - 1) mr = Cl - 1;
            asrc[j] = xb + (size_t)plist[lo + mr] * D_EMB + gq * 8;
        }
        f32x4 acc[4][4] = {};

        auto stage = [&](int kt, int buf) {
            const int k0 = kt * 64;
#pragma unroll
            for (int j = 0; j < 4; j++)
                gll16(asrc[j] + k0, &As[buf][j * 2048 + wave * 512]);
#pragma unroll
            for (int j = 0; j < 4; j++)
                gll16(bsrc[j] + k0, &Bs[buf][j * 2048 + wave * 512]);
        };
        auto compute = [&](int buf) {
#pragma unroll
            for (int kk = 0; kk < 2; kk++) {
                bfrag af[4], bf[4];
#pragma unroll
                for (int i = 0; i < 4; i++) {
                    int rowa = wr * 64 + i * 16 + r;
                    int rowb = wc * 64 + i * 16 + r;
                    int slot = ((qq + 4 * kk) ^ (r & 7)) * 8;
                    af[i] = *(const bfrag*)(&As[buf][rowa * 64 + slot]);
                    bf[i] = *(const bfrag*)(&Bs[buf][rowb * 64 + slot]);
                }
#pragma unroll
                for (int mi = 0; mi < 4; mi++)
#pragma unroll
                    for (int ni = 0; ni < 4; ni++)
                        acc[mi][ni] = mfma16(af[mi], bf[ni], acc[mi][ni]);
            }
        };

        waitv0();                        // drain prior epilogue stores (vmcnt-counted)
        stage(0, 0);
        for (int kt = 0; kt < 11; kt++) {
            stage(kt + 1, (kt + 1) & 1);
            waitv8(); sbar();            // tile kt landed everywhere; kt+1 in flight
            compute(kt & 1);
            sbar();                      // all reads of buf[kt&1] done
        }
        waitv0(); sbar();
        compute(1);                      // kt = 11

#pragma unroll
        for (int mi = 0; mi < 4; mi++)
#pragma unroll
            for (int ni = 0; ni < 4; ni++) {
                int col = n0 + wc * 64 + ni * 16 + r;
                float bias = b1[(size_t)e * F_HID + col];
#pragma unroll
                for (int i = 0; i < 4; i++) {
                    int m = m0 + wr * 64 + mi * 16 + qq * 4 + i;
                    if (m < Cl) {
                        float v = acc[mi][ni][i] + bias;
                        h[(size_t)(lo - P0 + m) * F_HID + col] = f2b(v > 0.f ? v : 0.f);
                    }
                }
            }
    }
}

// ---------------------------------------------------------------- FFN2 GEMM
// y[p] = h[p-P0] . w2t[e]^T + b2[e]  (plain stores, no atomics)
// 64x128 tile, BK=64, dbuf + counted-vmcnt pipeline, same swizzles as ffn1.
__global__ __launch_bounds__(256) void moe_ffn2_kernel(
    const u16* __restrict__ h, const u16* __restrict__ w2t, const float* __restrict__ b2,
    const int* __restrict__ cnt, const int* __restrict__ off,
    float* __restrict__ y, int P0, int P1)
{
    __shared__ __align__(16) u16 As[2][64 * 64];    // 2 x 8 KB
    __shared__ __align__(16) u16 Bs[2][128 * 64];   // 2 x 16 KB
    const int GX = 6, GY = 32;                      // grid = (6,32,8), nwg=1536
    int f = blockIdx.x + GX * (blockIdx.y + GY * blockIdx.z);
    int swz = (f & 7) * 192 + (f >> 3);             // chunk=192=one expert
    int nb = swz % GX;
    int t2 = swz / GX;
    int mb = t2 % GY;
    int e  = t2 / GY;

    int lo = off[e], hi = lo + cnt[e];
    if (lo < P0) lo = P0;
    if (hi > P1) hi = P1;
    const int Cl = hi - lo;
    if (Cl <= 0) return;
    const int n0 = nb * 128;
    const int tid = threadIdx.x;
    const int lane = tid & 63, wave = tid >> 6;
    const int wr = wave >> 1, wc = wave & 1;
    const int qq = lane >> 4, r = lane & 15;
    const int srow = tid >> 3;
    const int gq = (tid & 7) ^ (srow & 7);
    const int hcap = P1 - P0;

    const u16* bsrc[4];
#pragma unroll
    for (int j = 0; j < 4; j++)
        bsrc[j] = w2t + ((size_t)e * D_EMB + n0 + j * 32 + srow) * F_HID + gq * 8;

    for (int m0 = mb * 64; m0 < Cl; m0 += GY * 64) {
        const u16* asrc[2];
#pragma unroll
        for (int j = 0; j < 2; j++) {
            int mr = m0 + j * 32 + srow;
            if (mr > Cl - 1) mr = Cl - 1;
            asrc[j] = h + (size_t)(lo - P0 + ((mr < hcap) ? mr : hcap - 1)) * F_HID + gq * 8;
        }
        f32x4 acc[2][4] = {};

        auto stage = [&](int kt, int buf) {
            const int k0 = kt * 64;
#pragma unroll
            for (int j = 0; j < 2; j++)
                gll16(asrc[j] + k0, &As[buf][j * 2048 + wave * 512]);
#pragma unroll
            for (int j = 0; j < 4; j++)
                gll16(bsrc[j] + k0, &Bs[buf][j * 2048 + wave * 512]);
        };
        auto compute = [&](int buf) {
#pragma unroll
            for (int kk = 0; kk < 2; kk++) {
                bfrag af[2], bf[4];
#pragma unroll
                for (int i = 0; i < 2; i++) {
                    int rowa = wr * 32 + i * 16 + r;
                    int slot = ((qq + 4 * kk) ^ (r & 7)) * 8;
                    af[i] = *(const bfrag*)(&As[buf][rowa * 64 + slot]);
                }
#pragma unroll
                for (int i = 0; i < 4; i++) {
                    int rowb = wc * 64 + i * 16 + r;
                    int slot = ((qq + 4 * kk) ^ (r & 7)) * 8;
                    bf[i] = *(const bfrag*)(&Bs[buf][rowb * 64 + slot]);
                }
#pragma unroll
                for (int mi = 0; mi < 2; mi++)
#pragma unroll
                    for (int ni = 0; ni < 4; ni++)
                        acc[mi][ni] = mfma16(af[mi], bf[ni], acc[mi][ni]);
            }
        };

        waitv0();
        stage(0, 0);
        for (int kt = 0; kt < 47; kt++) {
            stage(kt + 1, (kt + 1) & 1);
            waitv6(); sbar();
            compute(kt & 1);
            sbar();
        }
        waitv0(); sbar();
        compute(1);                      // kt = 47

#pragma unroll
        for (int mi = 0; mi < 2; mi++)
#pragma unroll
            for (int ni = 0; ni < 4; ni++) {
                int col = n0 + wc * 64 + ni * 16 + r;
                float bias = b2[(size_t)e * D_EMB + col];
#pragma unroll
                for (int i = 0; i < 4; i++) {
                    int m = m0 + wr * 32 + mi * 16 + qq * 4 + i;
                    if (m < Cl)
                        y[(size_t)(lo + m) * D_EMB + col] = acc[mi][ni][i] + bias;
                }
            }
    }
}

// ---------------------------------------------------------------- combine
// out[t] = sum_k gate[t,k] * y[pos[t,k]]  (writes every token -> no zero pass)
__global__ __launch_bounds__(256) void moe_combine_kernel(
    const float* __restrict__ y, const int* __restrict__ tk_e,
    const float* __restrict__ tk_g, const int* __restrict__ pos,
    float4* __restrict__ out)
{
    int i = blockIdx.x * 256 + threadIdx.x;   // 786432 float4
    int t = i / 192;
    int c = i - t * 192;
    float4 a = make_float4(0.f, 0.f, 0.f, 0.f);
#pragma unroll
    for (int k = 0; k < 2; k++) {
        int e = tk_e[t * 2 + k];
        if (e >= 0) {
            float g = tk_g[t * 2 + k];
            float4 v = ((const float4*)(y + (size_t)pos[t * 2 + k] * D_EMB))[c];
            a.x += g * v.x; a.y += g * v.y; a.z += g * v.z; a.w += g * v.w;
        }
    }
    out[i] = a;
}

// ---------------------------------------------------------------- fallback fused FFN (fp32)
#define XSTR 776
#define HSTR 3080
#define BMF 8
__global__ __launch_bounds__(256) void moe_ffn_fused_f32(
    const float* __restrict__ x,
    const float* __restrict__ w1, const float* __restrict__ b1,
    const float* __restrict__ w2, const float* __restrict__ b2,
    const int* __restrict__ plist, const float* __restrict__ pg,
    const int* __restrict__ cnt, const int* __restrict__ off,
    float* __restrict__ out)
{
    __shared__ __align__(16) u16 xs[BMF * XSTR];
    __shared__ __align__(16) u16 hs[BMF * HSTR];
    const int e = blockIdx.x;
    const int Cl = cnt[e];
    if (Cl <= 0) return;
    const int O = off[e];
    const int tid = threadIdx.x;
    for (int t0 = blockIdx.y * BMF; t0 < Cl; t0 += gridDim.y * BMF) {
        for (int ci = tid; ci < BMF * 192; ci += 256) {
            int row = ci / 192, c = ci - row * 192;
            float4 v = make_float4(0.f, 0.f, 0.f, 0.f);
            if (t0 + row < Cl) {
                int tok = plist[O + t0 + row];
                v = *(const float4*)(x + (size_t)tok * D_EMB + c * 4);
            }
            u16* d = &xs[row * XSTR + c * 4];
            d[0] = f2b(v.x); d[1] = f2b(v.y); d[2] = f2b(v.z); d[3] = f2b(v.w);
        }
        __syncthreads();
        for (int wi = tid; wi < BMF * 768; wi += 256) {
            int row = wi / 768, nc = wi - row * 768;
            int n0 = nc * 4;
            float a0 = 0, a1 = 0, a2 = 0, a3 = 0;
            const float* wp = w1 + (size_t)e * D_EMB * F_HID + n0;
            const u16* xr = &xs[row * XSTR];
            for (int k = 0; k < D_EMB; k++) {
                float4 wv = *(const float4*)(wp + (size_t)k * F_HID);
                float xv = b2f(xr[k]);
                a0 += xv * wv.x; a1 += xv * wv.y; a2 += xv * wv.z; a3 += xv * wv.w;
            }
            const float* bp = b1 + (size_t)e * F_HID + n0;
            u16* hp = &hs[row * HSTR + n0];
            float v;
            v = a0 + bp[0]; hp[0] = f2b(v > 0.f ? v : 0.f);
            v = a1 + bp[1]; hp[1] = f2b(v > 0.f ? v : 0.f);
            v = a2 + bp[2]; hp[2] = f2b(v > 0.f ? v : 0.f);
            v = a3 + bp[3]; hp[3] = f2b(v > 0.f ? v : 0.f);
        }
        __syncthreads();
        for (int wi = tid; wi < BMF * 192; wi += 256) {
            int row = wi / 192, nc = wi - row * 192;
            int n0 = nc * 4;
            float a0 = 0, a1 = 0, a2 = 0, a3 = 0;
            const float* wp = w2 + (size_t)e * F_HID * D_EMB + n0;
            const u16* hr = &hs[row * HSTR];
            for (int k = 0; k < F_HID; k++) {
                float4 wv = *(const float4*)(wp + (size_t)k * D_EMB);
                float hv = b2f(hr[k]);
                a0 += hv * wv.x; a1 += hv * wv.y; a2 += hv * wv.z; a3 += hv * wv.w;
            }
            if (t0 + row < Cl) {
                int p = O + t0 + row;
                int tok = plist[p];
                float g = pg[p];
                const float* bp = b2 + (size_t)e * D_EMB + n0;
                float* op = out + (size_t)tok * D_EMB + n0;
                atomicAdd(&op[0], g * (a0 + bp[0]));
                atomicAdd(&op[1], g * (a1 + bp[1]));
                atomicAdd(&op[2], g * (a2 + bp[2]));
                atomicAdd(&op[3], g * (a3 + bp[3]));
            }
        }
        __syncthreads();
    }
}

// ---------------------------------------------------------------- launch
extern "C" void kernel_launch(void* const* d_in, const int* in_sizes, int n_in,
                              void* d_out, int out_size, void* d_ws, size_t ws_size,
                              hipStream_t stream) {
    const float* x     = (const float*)d_in[0];
    const float* noise = (const float*)d_in[1];
    const float* Wg    = (const float*)d_in[2];
    const float* bg    = (const float*)d_in[3];
    const float* Wn    = (const float*)d_in[4];
    const float* bn    = (const float*)d_in[5];
    const float* W1    = (const float*)d_in[6];
    const float* b1    = (const float*)d_in[7];
    const float* W2    = (const float*)d_in[8];
    const float* b2    = (const float*)d_in[9];
    float* out = (float*)d_out;

    // workspace layout
    char* ws = (char*)d_ws;
    int*   cnt    = (int*)(ws + 0);
    int*   off    = (int*)(ws + 256);
    int*   cursor = (int*)(ws + 512);
    int*   tk_e   = (int*)(ws + 1024);       // 32768 B
    float* tk_g   = (float*)(ws + 33792);    // 32768 B
    int*   plist  = (int*)(ws + 66560);      // 32768 B
    float* pg     = (float*)(ws + 99328);    // 32768 B
    int*   pos    = (int*)(ws + 132096);     // 32768 B
    const size_t W1T_OFF = 164864;                      // 8*3072*768*2 = 37748736
    const size_t W2T_OFF = W1T_OFF + 37748736ull;
    const size_t XB_OFF  = W2T_OFF + 37748736ull;       // xb: 4096*768*2 = 6291456
    const size_t Y_OFF   = XB_OFF + 6291456ull;         // y: 8192*768*4 = 25165824
    const size_t H_OFF   = Y_OFF + 25165824ull;         // h: pchunk*3072*2
    u16*   w1t = (u16*)(ws + W1T_OFF);
    u16*   w2t = (u16*)(ws + W2T_OFF);
    u16*   xb  = (u16*)(ws + XB_OFF);
    float* y   = (float*)(ws + Y_OFF);
    u16*   h   = (u16*)(ws + H_OFF);

    // largest h chunk that fits (0 => fallback path). Depends only on ws_size.
    int pchunk = 0;
    for (int p = N_PAIR; p >= 512; p >>= 1) {
        if (H_OFF + (size_t)p * F_HID * 2 <= ws_size) { pchunk = p; break; }
    }

    moe_init_kernel<<<dim3(1), dim3(64), 0, stream>>>(cnt);
    moe_router_v2<<<dim3(512), dim3(64), 0, stream>>>(
        x, noise, Wg, bg, Wn, bn, tk_e, tk_g, cnt);
    moe_offsets_kernel<<<dim3(1), dim3(64), 0, stream>>>(cnt, off, cursor);
    moe_scatter_kernel<<<dim3(N_PAIR / 256), dim3(256), 0, stream>>>(
        tk_e, tk_g, cursor, plist, pg, pos);

    if (pchunk > 0) {
        // fast path: MFMA grouped GEMMs, counted-vmcnt pipelined staging
        moe_cvtx_kernel<<<dim3(3072), dim3(256), 0, stream>>>(
            (const float4*)x, (ushort4*)xb);
        moe_transcvt_kernel<<<dim3(F_HID / 32, D_EMB / 32, 8), dim3(256), 0, stream>>>(
            W1, w1t, D_EMB, F_HID);   // [e][768][3072] -> [e][3072][768]
        moe_transcvt_kernel<<<dim3(D_EMB / 32, F_HID / 32, 8), dim3(256), 0, stream>>>(
            W2, w2t, F_HID, D_EMB);   // [e][3072][768] -> [e][768][3072]
        for (int c = 0; c < N_PAIR / pchunk; c++) {
            int P0 = c * pchunk, P1 = P0 + pchunk;
            moe_ffn1_kernel<<<dim3(24, 16, 8), dim3(256), 0, stream>>>(
                xb, w1t, b1, plist, cnt, off, h, P0, P1);
            moe_ffn2_kernel<<<dim3(6, 32, 8), dim3(256), 0, stream>>>(
                h, w2t, b2, cnt, off, y, P0, P1);
        }
        moe_combine_kernel<<<dim3(3072), dim3(256), 0, stream>>>(
            y, tk_e, tk_g, pos, (float4*)out);
    } else {
        moe_zero_kernel<<<dim3(3072), dim3(256), 0, stream>>>((uint4*)out);
        moe_ffn_fused_f32<<<dim3(8, 192), dim3(256), 0, stream>>>(
            x, W1, b1, W2, b2, plist, pg, cnt, off, out);
    }
    (void)in_sizes; (void)n_in; (void)out_size;
}